// Round 4
// baseline (1005.252 us; speedup 1.0000x reference)
//
#include <hip/hip_runtime.h>

// ---------------------------------------------------------------------------
// Fused per-sample attention-critic network, MI355X (gfx950).
// Wave-per-sample. Row-per-lane softmax (no cross-lane), DPP wave reductions,
// phase-local weight registers, V^T + f16-packed probs so PV uses fdot2.
// Arena: every phase has disjoint read/write regions (audited pairwise).
// ---------------------------------------------------------------------------

typedef __fp16 h2 __attribute__((ext_vector_type(2)));
typedef float4 f4a  __attribute__((may_alias));
typedef float2 f2a  __attribute__((may_alias));
typedef __fp16 f16a __attribute__((may_alias));

__device__ __forceinline__ h2 pkh2(float a, float b) {
#if __has_builtin(__builtin_amdgcn_cvt_pkrtz)
  return __builtin_amdgcn_cvt_pkrtz(a, b);
#else
  h2 r; r.x = (__fp16)a; r.y = (__fp16)b; return r;
#endif
}
__device__ __forceinline__ h2    f_h2(float f) { return __builtin_bit_cast(h2, f); }
__device__ __forceinline__ float h2_f(h2 v)    { return __builtin_bit_cast(float, v); }

__device__ __forceinline__ float fdot2(h2 a, h2 b, float c) {
#if __has_builtin(__builtin_amdgcn_fdot2)
  return __builtin_amdgcn_fdot2(a, b, c, false);
#else
  return c + (float)a.x * (float)b.x + (float)a.y * (float)b.y;
#endif
}
__device__ __forceinline__ float rcpf(float x) {
#if __has_builtin(__builtin_amdgcn_rcpf)
  return __builtin_amdgcn_rcpf(x);
#else
  return 1.f / x;
#endif
}
__device__ __forceinline__ float tanhf_fast(float x) {
  float e = __expf(2.f * x);
  return 1.f - 2.f * rcpf(e + 1.f);
}
__device__ __forceinline__ float eluf(float x) {
  return x > 0.f ? x : __expf(x) - 1.f;
}

// Full-wave (64-lane) f32 sum via DPP; result broadcast to all lanes.
__device__ __forceinline__ float wred_add(float x) {
#if __has_builtin(__builtin_amdgcn_update_dpp)
  float v = x;
  { int t = __builtin_amdgcn_update_dpp(0, __builtin_bit_cast(int, v), 0x111, 0xf, 0xf, true);
    v = v + __builtin_bit_cast(float, t); }   // row_shr:1
  { int t = __builtin_amdgcn_update_dpp(0, __builtin_bit_cast(int, v), 0x112, 0xf, 0xf, true);
    v = v + __builtin_bit_cast(float, t); }   // row_shr:2
  { int t = __builtin_amdgcn_update_dpp(0, __builtin_bit_cast(int, v), 0x114, 0xf, 0xf, true);
    v = v + __builtin_bit_cast(float, t); }   // row_shr:4
  { int t = __builtin_amdgcn_update_dpp(0, __builtin_bit_cast(int, v), 0x118, 0xf, 0xf, true);
    v = v + __builtin_bit_cast(float, t); }   // row_shr:8
  { int t = __builtin_amdgcn_update_dpp(0, __builtin_bit_cast(int, v), 0x142, 0xa, 0xf, true);
    v = v + __builtin_bit_cast(float, t); }   // row_bcast:15 -> rows 1,3
  { int t = __builtin_amdgcn_update_dpp(0, __builtin_bit_cast(int, v), 0x143, 0xc, 0xf, true);
    v = v + __builtin_bit_cast(float, t); }   // row_bcast:31 -> rows 2,3
  return __builtin_bit_cast(float, __builtin_amdgcn_readlane(__builtin_bit_cast(int, v), 63));
#else
  #pragma unroll
  for (int m2 = 1; m2 < 64; m2 <<= 1) x += __shfl_xor(x, m2, 64);
  return x;
#endif
}

// LayerNorm over a 1344-element f16 tensor held in LDS (NF4 f4-chunks of 8 f16).
// MODE 0: region element pos == reference flat index (K/Q layout [H*N][32]).
// MODE 1: V^T layout [96(hd)][16(n, 14 used)], pads are zero.
template<int NF4, int MODE>
__device__ __forceinline__ void doLN(h2* region, const float* __restrict__ gp,
                                     const float* __restrict__ bp, bool triv, int lane) {
  const f4a* tb = (const f4a*)region;
  const bool e2 = (NF4 == 192) ? true : (lane < (NF4 - 128));
  float4 r0 = tb[lane];
  float4 r1 = tb[lane + 64];
  float4 r2 = tb[e2 ? (lane + 128) : 0];
  if (!e2) { r2.x = 0.f; r2.y = 0.f; r2.z = 0.f; r2.w = 0.f; }
  h2 one2; one2.x = (__fp16)1.f; one2.y = (__fp16)1.f;
  float sum = 0.f, sq = 0.f;
  {
    float fb[12] = {r0.x,r0.y,r0.z,r0.w, r1.x,r1.y,r1.z,r1.w, r2.x,r2.y,r2.z,r2.w};
    #pragma unroll
    for (int i = 0; i < 12; ++i) { h2 a = f_h2(fb[i]); sum = fdot2(a, one2, sum); sq = fdot2(a, a, sq); }
  }
  sum = wred_add(sum); sq = wred_add(sq);
  const float mean = sum * (1.f / 1344.f);
  const float var  = sq  * (1.f / 1344.f) - mean * mean;
  const float sc   = rsqrtf(var + 1e-5f);
  const float msc  = -mean * sc;
  f4a* tbw = (f4a*)region;
  auto norm_store = [&](float4 rv, int o, bool en) {
    if (!en) return;
    h2 ha = f_h2(rv.x), hb = f_h2(rv.y), hc = f_h2(rv.z), hd = f_h2(rv.w);
    float f[8];
    f[0] = (float)ha.x * sc + msc; f[1] = (float)ha.y * sc + msc;
    f[2] = (float)hb.x * sc + msc; f[3] = (float)hb.y * sc + msc;
    f[4] = (float)hc.x * sc + msc; f[5] = (float)hc.y * sc + msc;
    f[6] = (float)hd.x * sc + msc; f[7] = (float)hd.y * sc + msc;
    if (!triv) {
      #pragma unroll
      for (int i = 0; i < 8; ++i) {
        int pos = 8 * o + i;
        int idx;
        if (MODE == 0) { idx = pos; }
        else { int nn = pos & 15, hd2 = pos >> 4;
               idx = (nn < 14) ? (((hd2 >> 5) * 14 + nn) * 32 + (hd2 & 31)) : -1; }
        if (idx >= 0) f[i] = f[i] * gp[idx] + bp[idx];
      }
    }
    float4 o4;
    o4.x = h2_f(pkh2(f[0], f[1])); o4.y = h2_f(pkh2(f[2], f[3]));
    o4.z = h2_f(pkh2(f[4], f[5])); o4.w = h2_f(pkh2(f[6], f[7]));
    tbw[o] = o4;
  };
  norm_store(r0, lane, true);
  norm_store(r1, lane + 64, true);
  norm_store(r2, lane + 128, e2);
}

// ---------------------------------------------------------------------------
// Arena (h2 units, 2096 total = 8384 B/wave, all f4 bases 16B-aligned):
//  xs   [0,72)       x sample f16 pairs              (live whole sample)
//  K    [80,752)     f16 [160,1504)                  (P1-P3)
//  Q    [752,1424)   f16 [1504,2848)                 (P1-P3)
//  S    [1424,2096)  f32 [42][16] scores             (P3-P4)
//  P'   [80,752)     f32 [42][16] alin out, overlays dead K   (P4-P5)
//  Pk   [848,1184)   f16 probs [42][8]h2, overlays dead Q     (P5-P7)
//  V^T  [80,848)     f16 [96][16], overlays dead P'           (P6-P7)
//  E    [1184,1856)  f16 [2368,3712) [14][96]                 (P7-P8)
//  E2   [424,872)    f32 [14][32], overlays dead V^T/Pk       (P8-P9)
// Phase read/write sets are pairwise disjoint (audited).
// ---------------------------------------------------------------------------
__global__ __launch_bounds__(256, 3) void fused_main(
    const float* __restrict__ x,
    const float* __restrict__ kw,   const float* __restrict__ kb,
    const float* __restrict__ qw,   const float* __restrict__ qb,
    const float* __restrict__ vw,   const float* __restrict__ vb,
    const float* __restrict__ kng,  const float* __restrict__ knb,
    const float* __restrict__ qng,  const float* __restrict__ qnb,
    const float* __restrict__ vng,  const float* __restrict__ vnb,
    const float* __restrict__ klinw, const float* __restrict__ klinb,
    const float* __restrict__ qlinw, const float* __restrict__ qlinb,
    const float* __restrict__ alinw, const float* __restrict__ alinb,
    const float* __restrict__ l1w,  const float* __restrict__ l1b,
    const float* __restrict__ l2w,  const float* __restrict__ l2b,
    float* __restrict__ out, int B)
{
  __shared__ h2    s_pw[1440];            // [288 cols][5 f16-pairs] k,q,v concat
  __shared__ float s_pb[288];
  __shared__ __align__(16) h2 s_qlw[224]; // [14][16]
  __shared__ __align__(16) h2 s_klw[224];
  __shared__ float s_bqk[16];
  __shared__ __align__(16) float s_alw[224]; // [14][16] f32, cols>=14 zero
  __shared__ float s_ab[16];
  __shared__ __align__(16) h2 s_l1w[1792];   // [32][56], 48 used
  __shared__ float s_l1b[32], s_l2w[32], s_l2b1[1];
  __shared__ unsigned s_gflags;
  __shared__ __align__(16) h2 s_arena[4][2096];

  const int tid = threadIdx.x;
  for (int i = tid; i < 1440; i += 256) {
    int C = i / 5, f2 = i - 5 * C;
    int t = C / 96, c = C - 96 * t;
    const float* w = (t == 0) ? kw : (t == 1) ? qw : vw;
    s_pw[i] = pkh2(w[c * 10 + 2 * f2], w[c * 10 + 2 * f2 + 1]);
  }
  for (int i = tid; i < 288; i += 256) {
    int t = i / 96, c = i - 96 * t;
    s_pb[i] = ((t == 0) ? kb : (t == 1) ? qb : vb)[c];
  }
  for (int i = tid; i < 224; i += 256) {
    int n = i >> 4, d2 = i & 15;
    s_qlw[i] = pkh2(qlinw[n * 32 + 2 * d2], qlinw[n * 32 + 2 * d2 + 1]);
    s_klw[i] = pkh2(klinw[n * 32 + 2 * d2], klinw[n * 32 + 2 * d2 + 1]);
    s_alw[i] = (d2 < 14) ? alinw[n * 14 + d2] : 0.f;
  }
  if (tid < 14)              { s_bqk[tid] = qlinb[tid] + klinb[tid]; s_ab[tid] = alinb[tid]; }
  if (tid >= 14 && tid < 16) { s_bqk[tid] = 0.f; s_ab[tid] = 0.f; }
  for (int i = tid; i < 1792; i += 256) {
    int j = i / 56, c2 = i - 56 * j;
    s_l1w[i] = (c2 < 48) ? pkh2(l1w[j * 96 + 2 * c2], l1w[j * 96 + 2 * c2 + 1])
                         : pkh2(0.f, 0.f);
  }
  if (tid < 32) { s_l1b[tid] = l1b[tid]; s_l2w[tid] = l2w[tid]; }
  if (tid == 0) { s_l2b1[0] = l2b[0]; s_gflags = 7u; }
  __syncthreads();
  for (int i = tid; i < 1344; i += 256) {
    if (kng[i] != 1.f || knb[i] != 0.f) atomicAnd(&s_gflags, ~1u);
    if (qng[i] != 1.f || qnb[i] != 0.f) atomicAnd(&s_gflags, ~2u);
    if (vng[i] != 1.f || vnb[i] != 0.f) atomicAnd(&s_gflags, ~4u);
  }
  __syncthreads();

  const int lane = tid & 63, wv = tid >> 6;
  h2*    arena = s_arena[wv];
  f16a*  af16  = (f16a*)arena;
  float* af32  = (float*)arena;
  h2*    xs    = arena;
  const unsigned gf = s_gflags;
  const int np = lane & 15, grp = lane >> 4;
  const int npc = (np < 14) ? np : 0;
  const int j32 = lane & 31, g2 = lane >> 5;

  // one-time scrub of S region (keeps never-written pad columns finite)
  for (int i = lane; i < 672; i += 64) af32[1424 + i] = 0.f;

  const int wgid = blockIdx.x * 4 + wv;
  const int wtot = gridDim.x * 4;

  float2 xcur0{}, xcur1{};
  if (wgid < B) {
    const f2a* xp = (const f2a*)(x + (size_t)wgid * 140);
    xcur0 = xp[lane];
    if (lane < 6) xcur1 = xp[64 + lane];
  }

  for (int s = wgid; s < B; s += wtot) {
    // ---- stage x; prefetch next sample ----
    xs[lane] = pkh2(xcur0.x, xcur0.y);
    if (lane < 6) xs[64 + lane] = pkh2(xcur1.x, xcur1.y);
    int sn = s + wtot;
    if (sn < B) {
      const f2a* xp = (const f2a*)(x + (size_t)sn * 140);
      xcur0 = xp[lane];
      if (lane < 6) xcur1 = xp[64 + lane];
    }

    // ---- P1: K,Q projections ----
    {
      h2 pwA[3][5]; float pbA[3]; int cbA[3];
      #pragma unroll
      for (int k = 0; k < 3; ++k) {
        int C = lane + 64 * k;
        #pragma unroll
        for (int f2 = 0; f2 < 5; ++f2) pwA[k][f2] = s_pw[C * 5 + f2];
        pbA[k] = s_pb[C];
        int t = (C >= 96) ? 1 : 0, c = C - 96 * t;
        cbA[k] = (t ? 1504 : 160) + (c >> 5) * 448 + (c & 31);   // f16 idx
      }
      #pragma unroll
      for (int n = 0; n < 14; ++n) {
        h2 x0 = xs[n*5+0], x1 = xs[n*5+1], x2 = xs[n*5+2], x3 = xs[n*5+3], x4 = xs[n*5+4];
        #pragma unroll
        for (int k = 0; k < 3; ++k) {
          float acc = pbA[k];
          acc = fdot2(x0, pwA[k][0], acc); acc = fdot2(x1, pwA[k][1], acc);
          acc = fdot2(x2, pwA[k][2], acc); acc = fdot2(x3, pwA[k][3], acc);
          acc = fdot2(x4, pwA[k][4], acc);
          af16[cbA[k] + n * 32] = (__fp16)acc;
        }
      }
    }
    // ---- P2: LN(K), LN(Q) ----
    doLN<168, 0>(arena + 80,  kng, knb, (gf >> 0) & 1u, lane);
    doLN<168, 0>(arena + 752, qng, qnb, (gf >> 1) & 1u, lane);

    // ---- P3: scores -> S f32 [42][16] @ f32 1424 ----
    {
      h2 qwr[16], kwr[16];
      const f4a* qp = (const f4a*)(s_qlw + npc * 16);
      const f4a* kp = (const f4a*)(s_klw + npc * 16);
      #pragma unroll
      for (int q = 0; q < 4; ++q) {
        float4 a = qp[q], b = kp[q];
        qwr[4*q+0] = f_h2(a.x); qwr[4*q+1] = f_h2(a.y); qwr[4*q+2] = f_h2(a.z); qwr[4*q+3] = f_h2(a.w);
        kwr[4*q+0] = f_h2(b.x); kwr[4*q+1] = f_h2(b.y); kwr[4*q+2] = f_h2(b.z); kwr[4*q+3] = f_h2(b.w);
      }
      const float bqkr = s_bqk[npc];
      for (int k = 0; k <= 10; ++k) {
        int r = grp + 4 * k;
        bool act = (np < 14) && (r < 42);
        int rr = (r < 42) ? r : 0;
        const f4a* Kr = (const f4a*)(arena + 80 + rr * 16);
        const f4a* Qr = (const f4a*)(arena + 752 + rr * 16);
        float accq = bqkr, acck = 0.f;
        #pragma unroll
        for (int q = 0; q < 4; ++q) {
          float4 qv = Qr[q], kv = Kr[q];
          accq = fdot2(f_h2(qv.x), qwr[4*q+0], accq);
          accq = fdot2(f_h2(qv.y), qwr[4*q+1], accq);
          accq = fdot2(f_h2(qv.z), qwr[4*q+2], accq);
          accq = fdot2(f_h2(qv.w), qwr[4*q+3], accq);
          acck = fdot2(f_h2(kv.x), kwr[4*q+0], acck);
          acck = fdot2(f_h2(kv.y), kwr[4*q+1], acck);
          acck = fdot2(f_h2(kv.z), kwr[4*q+2], acck);
          acck = fdot2(f_h2(kv.w), kwr[4*q+3], acck);
        }
        float a = eluf(accq + acck);
        if (act) af32[1424 + rr * 16 + np] = a;
      }
    }
    // ---- P4: alin -> P' f32 @ f32 80 (overlays dead K) ----
    {
      float awr[16];
      const f4a* ap = (const f4a*)(s_alw + npc * 16);
      #pragma unroll
      for (int q = 0; q < 4; ++q) {
        float4 v = ap[q];
        awr[4*q+0] = v.x; awr[4*q+1] = v.y; awr[4*q+2] = v.z; awr[4*q+3] = v.w;
      }
      const float abr = s_ab[npc];
      for (int k = 0; k <= 10; ++k) {
        int r = grp + 4 * k;
        bool act = (np < 14) && (r < 42);
        int rr = (r < 42) ? r : 0;
        const f4a* Sr = (const f4a*)(af32 + 1424 + rr * 16);
        float4 P0 = Sr[0], P1 = Sr[1], P2 = Sr[2], P3 = Sr[3];
        float acc = abr;
        acc += P0.x*awr[0]  + P0.y*awr[1]  + P0.z*awr[2]  + P0.w*awr[3];
        acc += P1.x*awr[4]  + P1.y*awr[5]  + P1.z*awr[6]  + P1.w*awr[7];
        acc += P2.x*awr[8]  + P2.y*awr[9]  + P2.z*awr[10] + P2.w*awr[11];
        acc += P3.x*awr[12] + P3.y*awr[13];
        if (act) af32[80 + rr * 16 + np] = acc;
      }
    }
    // ---- P5: softmax row-per-lane; Pk f16 [42][8]h2 @ h2 848 (overlays dead Q) ----
    if (lane < 42) {
      const f4a* Pr = (const f4a*)(af32 + 80 + lane * 16);
      float4 a0 = Pr[0], a1 = Pr[1], a2 = Pr[2], a3 = Pr[3];
      float mx = fmaxf(fmaxf(fmaxf(a0.x,a0.y), fmaxf(a0.z,a0.w)),
                 fmaxf(fmaxf(fmaxf(a1.x,a1.y), fmaxf(a1.z,a1.w)),
                 fmaxf(fmaxf(fmaxf(a2.x,a2.y), fmaxf(a2.z,a2.w)), fmaxf(a3.x,a3.y))));
      float e0 = __expf(a0.x-mx), e1 = __expf(a0.y-mx), e2 = __expf(a0.z-mx), e3 = __expf(a0.w-mx);
      float e4 = __expf(a1.x-mx), e5 = __expf(a1.y-mx), e6 = __expf(a1.z-mx), e7 = __expf(a1.w-mx);
      float e8 = __expf(a2.x-mx), e9 = __expf(a2.y-mx), eA = __expf(a2.z-mx), eB = __expf(a2.w-mx);
      float eC = __expf(a3.x-mx), eD = __expf(a3.y-mx);
      float sm = ((e0+e1)+(e2+e3)) + ((e4+e5)+(e6+e7)) + ((e8+e9)+(eA+eB)) + (eC+eD);
      float rs = rcpf(sm);
      float4 w0, w1;
      w0.x = h2_f(pkh2(e0*rs, e1*rs)); w0.y = h2_f(pkh2(e2*rs, e3*rs));
      w0.z = h2_f(pkh2(e4*rs, e5*rs)); w0.w = h2_f(pkh2(e6*rs, e7*rs));
      w1.x = h2_f(pkh2(e8*rs, e9*rs)); w1.y = h2_f(pkh2(eA*rs, eB*rs));
      w1.z = h2_f(pkh2(eC*rs, eD*rs)); w1.w = h2_f(pkh2(0.f, 0.f));
      f4a* Pko = (f4a*)(arena + 848 + lane * 8);
      Pko[0] = w0; Pko[1] = w1;
    }
    // ---- P6: V projection -> V^T [96][16]f16 @ h2 80 (overlays dead P') ----
    {
      h2 pwB[2][5]; float pbB[2]; bool actB[2]; int cB[2];
      #pragma unroll
      for (int k = 0; k < 2; ++k) {
        int c = lane + 64 * k;
        actB[k] = (c < 96);
        int cc = actB[k] ? c : 0;
        #pragma unroll
        for (int f2 = 0; f2 < 5; ++f2) pwB[k][f2] = s_pw[(192 + cc) * 5 + f2];
        pbB[k] = s_pb[192 + cc];
        cB[k] = cc;
      }
      float accV[2][14];
      #pragma unroll
      for (int n = 0; n < 14; ++n) {
        h2 x0 = xs[n*5+0], x1 = xs[n*5+1], x2 = xs[n*5+2], x3 = xs[n*5+3], x4 = xs[n*5+4];
        #pragma unroll
        for (int k = 0; k < 2; ++k) {
          float acc = pbB[k];
          acc = fdot2(x0, pwB[k][0], acc); acc = fdot2(x1, pwB[k][1], acc);
          acc = fdot2(x2, pwB[k][2], acc); acc = fdot2(x3, pwB[k][3], acc);
          acc = fdot2(x4, pwB[k][4], acc);
          accV[k][n] = acc;
        }
      }
      #pragma unroll
      for (int k = 0; k < 2; ++k) {
        if (!actB[k]) continue;
        float4 w0, w1;
        w0.x = h2_f(pkh2(accV[k][0],  accV[k][1]));  w0.y = h2_f(pkh2(accV[k][2],  accV[k][3]));
        w0.z = h2_f(pkh2(accV[k][4],  accV[k][5]));  w0.w = h2_f(pkh2(accV[k][6],  accV[k][7]));
        w1.x = h2_f(pkh2(accV[k][8],  accV[k][9]));  w1.y = h2_f(pkh2(accV[k][10], accV[k][11]));
        w1.z = h2_f(pkh2(accV[k][12], accV[k][13])); w1.w = h2_f(pkh2(0.f, 0.f));
        f4a* vo = (f4a*)(arena + 80 + cB[k] * 8);
        vo[0] = w0; vo[1] = w1;
      }
    }
    doLN<192, 1>(arena + 80, vng, vnb, (gf >> 2) & 1u, lane);

    // ---- P7: E[n][hd] = sum_m Pk[r][m] * V^T[hd][m] -> E f16 @ f16 2368 ----
    for (int k = 0; k <= 10; ++k) {
      int r = grp + 4 * k;
      bool act = (r < 42);
      int rr = act ? r : 0;
      int h = rr / 14, n = rr - 14 * h;
      const f4a* Pk4 = (const f4a*)(arena + 848 + rr * 8);
      float4 pa = Pk4[0], pb2 = Pk4[1];
      const f4a* vt0 = (const f4a*)(arena + 80 + (h * 32 + np) * 8);
      const f4a* vt1 = (const f4a*)(arena + 80 + (h * 32 + np + 16) * 8);
      float4 va = vt0[0], vb4 = vt0[1], vc = vt1[0], vd4 = vt1[1];
      float acc0 = 0.f, acc1 = 0.f;
      acc0 = fdot2(f_h2(pa.x), f_h2(va.x), acc0);  acc1 = fdot2(f_h2(pa.x), f_h2(vc.x), acc1);
      acc0 = fdot2(f_h2(pa.y), f_h2(va.y), acc0);  acc1 = fdot2(f_h2(pa.y), f_h2(vc.y), acc1);
      acc0 = fdot2(f_h2(pa.z), f_h2(va.z), acc0);  acc1 = fdot2(f_h2(pa.z), f_h2(vc.z), acc1);
      acc0 = fdot2(f_h2(pa.w), f_h2(va.w), acc0);  acc1 = fdot2(f_h2(pa.w), f_h2(vc.w), acc1);
      acc0 = fdot2(f_h2(pb2.x), f_h2(vb4.x), acc0); acc1 = fdot2(f_h2(pb2.x), f_h2(vd4.x), acc1);
      acc0 = fdot2(f_h2(pb2.y), f_h2(vb4.y), acc0); acc1 = fdot2(f_h2(pb2.y), f_h2(vd4.y), acc1);
      acc0 = fdot2(f_h2(pb2.z), f_h2(vb4.z), acc0); acc1 = fdot2(f_h2(pb2.z), f_h2(vd4.z), acc1);
      if (act) {
        af16[2368 + n * 96 + h * 32 + np]      = (__fp16)acc0;
        af16[2368 + n * 96 + h * 32 + np + 16] = (__fp16)acc1;
      }
    }
    // ---- P8: l1 -> E2 f32 [14][32] @ f32 424 (overlays dead V^T/Pk) ----
    {
      const float l1br = s_l1b[j32];
      for (int k = 0; k < 7; ++k) {
        int n = g2 + 2 * k;
        const f4a* Er = (const f4a*)(arena + 1184 + n * 48);
        const f4a* Lr = (const f4a*)(s_l1w + j32 * 56);
        float acc0 = l1br, acc1 = 0.f;
        #pragma unroll
        for (int q = 0; q < 12; ++q) {
          float4 ev = Er[q], lv = Lr[q];
          acc0 = fdot2(f_h2(ev.x), f_h2(lv.x), acc0);
          acc1 = fdot2(f_h2(ev.y), f_h2(lv.y), acc1);
          acc0 = fdot2(f_h2(ev.z), f_h2(lv.z), acc0);
          acc1 = fdot2(f_h2(ev.w), f_h2(lv.w), acc1);
        }
        af32[424 + n * 32 + j32] = fmaxf(acc0 + acc1, 0.f);
      }
    }
    // ---- P9: LN2 (448, no affine) + max_n + l2 -> y ----
    {
      float vals[7];
      #pragma unroll
      for (int m = 0; m < 7; ++m) vals[m] = af32[424 + lane + 64 * m];
      float sum2 = 0.f, sq2 = 0.f;
      #pragma unroll
      for (int m = 0; m < 7; ++m) { sum2 += vals[m]; sq2 += vals[m] * vals[m]; }
      sum2 = wred_add(sum2); sq2 = wred_add(sq2);
      float mean2 = sum2 * (1.f / 448.f);
      float var2  = sq2  * (1.f / 448.f) - mean2 * mean2;
      float sc2   = rsqrtf(var2 + 1e-5f);
      float mx = vals[0];
      #pragma unroll
      for (int m = 1; m < 7; ++m) mx = fmaxf(mx, vals[m]);
      mx = fmaxf(mx, __shfl_xor(mx, 32, 64));
      float Md = (mx - mean2) * sc2;            // scale>0: max commutes with LN
      float l2r = s_l2w[j32];
      float tot = wred_add((lane < 32) ? Md * l2r : 0.f);
      float yy = eluf(tot + s_l2b1[0]);
      if (lane == 0) out[s] = yy;
    }
  }
}

// ---------------------------------------------------------------------------
// Kernel 2: out[s] = sigmoid(fc3 . tanh(fc2 . tanh(fc1*y+b1) + b2) + b3)
// ---------------------------------------------------------------------------
__global__ __launch_bounds__(256) void mlp_head(
    float* __restrict__ out,
    const float* __restrict__ fc1w, const float* __restrict__ fc1b,
    const float* __restrict__ fc2w, const float* __restrict__ fc2b,
    const float* __restrict__ fc3w, const float* __restrict__ fc3b, int B)
{
  __shared__ float s1w[100], s1b[100];
  __shared__ __align__(16) h2 s2w[100 * 52];
  __shared__ float s2b[100], s3w[100];
  __shared__ float s3b[1];
  const int tid = threadIdx.x;
  for (int i = tid; i < 100; i += 256) {
    s1w[i] = fc1w[i]; s1b[i] = fc1b[i]; s2b[i] = fc2b[i]; s3w[i] = fc3w[i];
  }
  for (int i = tid; i < 5200; i += 256) {
    int r = i / 52, c2 = i - 52 * r;
    s2w[i] = (c2 < 50) ? pkh2(fc2w[r * 100 + 2 * c2], fc2w[r * 100 + 2 * c2 + 1])
                       : pkh2(0.f, 0.f);
  }
  if (tid == 0) s3b[0] = fc3b[0];
  __syncthreads();

  const int sid = blockIdx.x * 256 + tid;
  if (sid >= B) return;
  const float y = out[sid];

  h2 a6[52];
  #pragma unroll
  for (int j2 = 0; j2 < 50; ++j2) {
    float t0 = tanhf_fast(y * s1w[2 * j2]     + s1b[2 * j2]);
    float t1 = tanhf_fast(y * s1w[2 * j2 + 1] + s1b[2 * j2 + 1]);
    a6[j2] = pkh2(t0, t1);
  }
  a6[50] = pkh2(0.f, 0.f);
  a6[51] = pkh2(0.f, 0.f);

  float logit = s3b[0];
  for (int i = 0; i < 100; ++i) {
    const f4a* row = (const f4a*)(s2w + i * 52);
    float acc0 = s2b[i], acc1 = 0.f;
    #pragma unroll
    for (int q = 0; q < 13; ++q) {
      float4 rv = row[q];
      acc0 = fdot2(f_h2(rv.x), a6[4*q+0], acc0);
      acc1 = fdot2(f_h2(rv.y), a6[4*q+1], acc1);
      acc0 = fdot2(f_h2(rv.z), a6[4*q+2], acc0);
      acc1 = fdot2(f_h2(rv.w), a6[4*q+3], acc1);
    }
    logit += tanhf_fast(acc0 + acc1) * s3w[i];
  }
  out[sid] = rcpf(1.f + __expf(-logit));
}

// ---------------------------------------------------------------------------
extern "C" void kernel_launch(void* const* d_in, const int* in_sizes, int n_in,
                              void* d_out, int out_size, void* d_ws, size_t ws_size,
                              hipStream_t stream) {
  (void)d_ws; (void)ws_size; (void)n_in; (void)out_size;
  const float* x     = (const float*)d_in[0];
  const float* kw    = (const float*)d_in[1];
  const float* kb    = (const float*)d_in[2];
  const float* qw    = (const float*)d_in[3];
  const float* qb    = (const float*)d_in[4];
  const float* vw    = (const float*)d_in[5];
  const float* vb    = (const float*)d_in[6];
  const float* kng   = (const float*)d_in[7];
  const float* knb   = (const float*)d_in[8];
  const float* qng   = (const float*)d_in[9];
  const float* qnb   = (const float*)d_in[10];
  const float* vng   = (const float*)d_in[11];
  const float* vnb   = (const float*)d_in[12];
  const float* klinw = (const float*)d_in[13];
  const float* klinb = (const float*)d_in[14];
  const float* qlinw = (const float*)d_in[15];
  const float* qlinb = (const float*)d_in[16];
  const float* alinw = (const float*)d_in[17];
  const float* alinb = (const float*)d_in[18];
  const float* l1w   = (const float*)d_in[19];
  const float* l1b   = (const float*)d_in[20];
  const float* l2w   = (const float*)d_in[21];
  const float* l2b   = (const float*)d_in[22];
  const float* fc1w  = (const float*)d_in[23];
  const float* fc1b  = (const float*)d_in[24];
  const float* fc2w  = (const float*)d_in[25];
  const float* fc2b  = (const float*)d_in[26];
  const float* fc3w  = (const float*)d_in[27];
  const float* fc3b  = (const float*)d_in[28];
  float* out = (float*)d_out;
  const int B = in_sizes[0] / 140;

  fused_main<<<768, 256, 0, stream>>>(x, kw, kb, qw, qb, vw, vb,
      kng, knb, qng, qnb, vng, vnb, klinw, klinb, qlinw, qlinb,
      alinw, alinb, l1w, l1b, l2w, l2b, out, B);
  mlp_head<<<(B + 255) / 256, 256, 0, stream>>>(out, fc1w, fc1b, fc2w, fc2b,
      fc3w, fc3b, B);
}

// Round 5
// 568.785 us; speedup vs baseline: 1.7674x; 1.7674x over previous
//
#include <hip/hip_runtime.h>

// ---------------------------------------------------------------------------
// Fused per-sample attention-critic network, MI355X (gfx950).
// Base = round-1 kernel (verified clean: no spills, no conflicts) with the
// round-2 phase-split overlay (verified correct) to cut LDS -> 3 blocks/CU.
// Weights stay in LDS (r1-style); __launch_bounds__(256,3) so no VGPR spill.
// ---------------------------------------------------------------------------

typedef __fp16 h2 __attribute__((ext_vector_type(2)));
typedef h2     h2a  __attribute__((may_alias));
typedef float4 f4a  __attribute__((may_alias));
typedef float2 f2a  __attribute__((may_alias));
typedef __fp16 f16a __attribute__((may_alias));

__device__ __forceinline__ h2 pkh2(float a, float b) {
#if __has_builtin(__builtin_amdgcn_cvt_pkrtz)
  return __builtin_amdgcn_cvt_pkrtz(a, b);
#else
  h2 r; r.x = (__fp16)a; r.y = (__fp16)b; return r;
#endif
}
__device__ __forceinline__ h2    f_h2(float f) { return __builtin_bit_cast(h2, f); }
__device__ __forceinline__ float h2_f(h2 v)    { return __builtin_bit_cast(float, v); }

__device__ __forceinline__ float fdot2(h2 a, h2 b, float c) {
#if __has_builtin(__builtin_amdgcn_fdot2)
  return __builtin_amdgcn_fdot2(a, b, c, false);
#else
  return c + (float)a.x * (float)b.x + (float)a.y * (float)b.y;
#endif
}
__device__ __forceinline__ float rcpf(float x) {
#if __has_builtin(__builtin_amdgcn_rcpf)
  return __builtin_amdgcn_rcpf(x);
#else
  return 1.f / x;
#endif
}
__device__ __forceinline__ float tanhf_fast(float x) {
  float e = __expf(2.f * x);                 // inf-safe
  return 1.f - 2.f * rcpf(e + 1.f);
}
__device__ __forceinline__ float eluf(float x) {
  return x > 0.f ? x : __expf(x) - 1.f;
}

// ---------------------------------------------------------------------------
// Kernel 1: everything up to y = elu(E_max . l2_w + l2_b); y written to out[s]
// ---------------------------------------------------------------------------
__global__ __launch_bounds__(256, 3) void fused_main(
    const float* __restrict__ x,
    const float* __restrict__ kw,   const float* __restrict__ kb,
    const float* __restrict__ qw,   const float* __restrict__ qb,
    const float* __restrict__ vw,   const float* __restrict__ vb,
    const float* __restrict__ kng,  const float* __restrict__ knb,
    const float* __restrict__ qng,  const float* __restrict__ qnb,
    const float* __restrict__ vng,  const float* __restrict__ vnb,
    const float* __restrict__ klinw, const float* __restrict__ klinb,
    const float* __restrict__ qlinw, const float* __restrict__ qlinb,
    const float* __restrict__ alinw, const float* __restrict__ alinb,
    const float* __restrict__ l1w,  const float* __restrict__ l1b,
    const float* __restrict__ l2w,  const float* __restrict__ l2b,
    float* __restrict__ out, int B)
{
  // ---- block-shared weights (identical to round-1) ----
  __shared__ h2    s_pw[288 * 5];          // [C][f2], C = t*96 + c (k,q,v concat)
  __shared__ float s_pb[288];
  __shared__ __align__(16) h2 s_qlw[14 * 16];
  __shared__ __align__(16) h2 s_klw[14 * 16];
  __shared__ float s_bqk[16];
  __shared__ __align__(16) float s_alw[14 * 16];
  __shared__ float s_ab[16];
  __shared__ h2    s_l1w[32 * 50];         // stride 50 h2 = 100B (conflict-free)
  __shared__ float s_l1b[32];
  __shared__ float s_l2w[32];
  __shared__ float s_l2b[1];
  __shared__ unsigned s_gflags;
  // ---- per-wave sample state (phase-split overlay) ----
  __shared__ __align__(16) h2    s_kqv[4][1344]; // A: K@[0,672) Q@[672,1344)
                                                 // B: V@[0,672) E@[672,1344)
  __shared__ __align__(16) float s_A[4][672];    // scores/probs [42][16]; E2 [14][32]
  __shared__ h2    s_xs[4][72];

  const int tid = threadIdx.x;

  for (int i = tid; i < 1440; i += 256) {
    int C = i / 5, f2 = i - 5 * C;
    int t = C / 96, c = C - 96 * t;
    const float* w = (t == 0) ? kw : (t == 1) ? qw : vw;
    s_pw[i] = pkh2(w[c * 10 + 2 * f2], w[c * 10 + 2 * f2 + 1]);
  }
  for (int i = tid; i < 288; i += 256) {
    int t = i / 96, c = i - 96 * t;
    s_pb[i] = ((t == 0) ? kb : (t == 1) ? qb : vb)[c];
  }
  for (int i = tid; i < 224; i += 256) {
    int n = i >> 4, d2 = i & 15;
    s_qlw[i] = pkh2(qlinw[n * 32 + 2 * d2], qlinw[n * 32 + 2 * d2 + 1]);
    s_klw[i] = pkh2(klinw[n * 32 + 2 * d2], klinw[n * 32 + 2 * d2 + 1]);
    s_alw[i] = (d2 < 14) ? alinw[n * 14 + d2] : 0.f;
  }
  if (tid < 14)             { s_bqk[tid] = qlinb[tid] + klinb[tid]; s_ab[tid] = alinb[tid]; }
  if (tid >= 14 && tid < 16){ s_bqk[tid] = 0.f; s_ab[tid] = 0.f; }
  for (int i = tid; i < 1600; i += 256) {
    int j = i / 50, c2 = i - 50 * j;
    s_l1w[i] = (c2 < 48) ? pkh2(l1w[j * 96 + 2 * c2], l1w[j * 96 + 2 * c2 + 1])
                         : pkh2(0.f, 0.f);
  }
  if (tid < 32) { s_l1b[tid] = l1b[tid]; s_l2w[tid] = l2w[tid]; }
  if (tid == 0) { s_l2b[0] = l2b[0]; s_gflags = 7u; }
  __syncthreads();
  for (int i = tid; i < 1344; i += 256) {
    if (kng[i] != 1.f || knb[i] != 0.f) atomicAnd(&s_gflags, ~1u);
    if (qng[i] != 1.f || qnb[i] != 0.f) atomicAnd(&s_gflags, ~2u);
    if (vng[i] != 1.f || vnb[i] != 0.f) atomicAnd(&s_gflags, ~4u);
  }
  __syncthreads();

  const int lane = tid & 63;
  const int wv   = tid >> 6;
  h2*    kqv  = s_kqv[wv];
  f16a*  kqvh = (f16a*)kqv;
  float* Ab   = s_A[wv];
  h2*    xs   = s_xs[wv];
  const unsigned gf = s_gflags;

  // ---- persistent per-lane weight registers (from LDS, r1 pattern) ----
  // phase A: K(96)+Q(96) columns, C = lane + 64k, k<3, all active
  h2 pwA[3][5]; float pbA[3]; int cbA[3];
  #pragma unroll
  for (int k = 0; k < 3; ++k) {
    int C = lane + 64 * k;
    #pragma unroll
    for (int f2 = 0; f2 < 5; ++f2) pwA[k][f2] = s_pw[C * 5 + f2];
    pbA[k] = s_pb[C];
    int t = (C >= 96) ? 1 : 0, c = C - 96 * t;
    cbA[k] = t * 1344 + (c >> 5) * 448 + (c & 31);   // f16 element index, + n*32
  }
  // phase B: V columns c = lane + 64k, k<2 (96 of 128 active)
  h2 pwB[2][5]; float pbB[2]; int cbB[2]; bool actB[2];
  #pragma unroll
  for (int k = 0; k < 2; ++k) {
    int c = lane + 64 * k;
    actB[k] = (c < 96);
    int cc = actB[k] ? c : 0;
    #pragma unroll
    for (int f2 = 0; f2 < 5; ++f2) pwB[k][f2] = s_pw[(192 + cc) * 5 + f2];
    pbB[k] = s_pb[192 + cc];
    cbB[k] = (cc >> 5) * 448 + (cc & 31);
  }
  const int np  = lane & 15, grp = lane >> 4;
  const int npc = (np < 14) ? np : 0;
  h2 qwr[16], kwr[16];
  #pragma unroll
  for (int i = 0; i < 16; ++i) { qwr[i] = s_qlw[npc * 16 + i]; kwr[i] = s_klw[npc * 16 + i]; }
  const float bqkr = s_bqk[npc];
  float awr[14];
  #pragma unroll
  for (int i = 0; i < 14; ++i) awr[i] = s_alw[npc * 16 + i];
  const float abr  = s_ab[npc];
  const int j32 = lane & 31, g2 = lane >> 5;
  const float l1br = s_l1b[j32];
  const float l2r  = s_l2w[j32];
  const float l2bb = s_l2b[0];

  h2 one2; one2.x = (__fp16)1.f; one2.y = (__fp16)1.f;
  const bool has3 = (lane < 40);               // 168 f4 chunks = 64+64+40

  // LayerNorm over one 1344-f16 tensor at kqv h2 offset `base`
  // (element position within region == reference flat index [H][N][32])
  auto doLN = [&](int base, const float* gp, const float* bp, bool triv) {
    const f4a* tb = (const f4a*)(kqv + base);
    float4 r0 = tb[lane];
    float4 r1 = tb[lane + 64];
    float4 r2 = tb[has3 ? (lane + 128) : 0];
    if (!has3) { r2.x = 0.f; r2.y = 0.f; r2.z = 0.f; r2.w = 0.f; }
    float sum = 0.f, sq = 0.f;
    auto acc2 = [&](float fb) { h2 a = f_h2(fb); sum = fdot2(a, one2, sum); sq = fdot2(a, a, sq); };
    acc2(r0.x); acc2(r0.y); acc2(r0.z); acc2(r0.w);
    acc2(r1.x); acc2(r1.y); acc2(r1.z); acc2(r1.w);
    acc2(r2.x); acc2(r2.y); acc2(r2.z); acc2(r2.w);
    #pragma unroll
    for (int m2 = 1; m2 < 64; m2 <<= 1) { sum += __shfl_xor(sum, m2, 64); sq += __shfl_xor(sq, m2, 64); }
    const float mean = sum * (1.f / 1344.f);
    const float var  = sq  * (1.f / 1344.f) - mean * mean;
    const float sc   = rsqrtf(var + 1e-5f);
    const float msc  = -mean * sc;
    f4a* tbw = (f4a*)(kqv + base);
    auto norm_store = [&](float4 rv, int o, bool en) {
      if (!en) return;
      h2 ha = f_h2(rv.x), hb = f_h2(rv.y), hc = f_h2(rv.z), hd = f_h2(rv.w);
      float f0 = (float)ha.x * sc + msc, f1 = (float)ha.y * sc + msc;
      float f2v = (float)hb.x * sc + msc, f3 = (float)hb.y * sc + msc;
      float f4v = (float)hc.x * sc + msc, f5 = (float)hc.y * sc + msc;
      float f6 = (float)hd.x * sc + msc, f7 = (float)hd.y * sc + msc;
      if (!triv) {
        int e0 = 8 * o;
        f0 = f0 * gp[e0+0] + bp[e0+0]; f1 = f1 * gp[e0+1] + bp[e0+1];
        f2v = f2v * gp[e0+2] + bp[e0+2]; f3 = f3 * gp[e0+3] + bp[e0+3];
        f4v = f4v * gp[e0+4] + bp[e0+4]; f5 = f5 * gp[e0+5] + bp[e0+5];
        f6 = f6 * gp[e0+6] + bp[e0+6]; f7 = f7 * gp[e0+7] + bp[e0+7];
      }
      float4 o4;
      o4.x = h2_f(pkh2(f0, f1)); o4.y = h2_f(pkh2(f2v, f3));
      o4.z = h2_f(pkh2(f4v, f5)); o4.w = h2_f(pkh2(f6, f7));
      tbw[o] = o4;
    };
    norm_store(r0, lane, true);
    norm_store(r1, lane + 64, true);
    norm_store(r2, lane + 128, has3);
  };

  const int wgid = blockIdx.x * 4 + wv;
  const int wtot = gridDim.x * 4;

  for (int s = wgid; s < B; s += wtot) {
    // ---------------- stage x (140 f32 -> 70 f16 pairs) ----------------
    const f2a* xp = (const f2a*)(x + (size_t)s * 140);
    { f2a v = xp[lane]; xs[lane] = pkh2(v.x, v.y); }
    if (lane < 6) { f2a v = xp[64 + lane]; xs[64 + lane] = pkh2(v.x, v.y); }

    // ============ PHASE A: K,Q projections -> LN -> scores -> softmax ======
    for (int n = 0; n < 14; ++n) {
      h2 xr0 = xs[n*5+0], xr1 = xs[n*5+1], xr2 = xs[n*5+2], xr3 = xs[n*5+3], xr4 = xs[n*5+4];
      #pragma unroll
      for (int k = 0; k < 3; ++k) {
        float acc = pbA[k];
        acc = fdot2(xr0, pwA[k][0], acc);
        acc = fdot2(xr1, pwA[k][1], acc);
        acc = fdot2(xr2, pwA[k][2], acc);
        acc = fdot2(xr3, pwA[k][3], acc);
        acc = fdot2(xr4, pwA[k][4], acc);
        kqvh[cbA[k] + n * 32] = (__fp16)acc;
      }
    }
    doLN(0,   kng, knb, (gf >> 0) & 1u);   // K
    doLN(672, qng, qnb, (gf >> 1) & 1u);   // Q

    // ------- scores: A0[r][n'] = elu(Q[r]·qlw[n'] + K[r]·klw[n'] + b) -------
    for (int k = 0; k <= 10; ++k) {
      int r = grp + 4 * k;
      bool act = (np < 14) && (r < 42);
      int rr = (r < 42) ? r : 0;
      const f4a* Kr = (const f4a*)(kqv + rr * 16);
      const f4a* Qr = (const f4a*)(kqv + 672 + rr * 16);
      float accq = bqkr, acck = 0.f;
      #pragma unroll
      for (int q = 0; q < 4; ++q) {
        float4 qv = Qr[q], kv = Kr[q];
        accq = fdot2(f_h2(qv.x), qwr[4*q+0], accq);
        accq = fdot2(f_h2(qv.y), qwr[4*q+1], accq);
        accq = fdot2(f_h2(qv.z), qwr[4*q+2], accq);
        accq = fdot2(f_h2(qv.w), qwr[4*q+3], accq);
        acck = fdot2(f_h2(kv.x), kwr[4*q+0], acck);
        acck = fdot2(f_h2(kv.y), kwr[4*q+1], acck);
        acck = fdot2(f_h2(kv.z), kwr[4*q+2], acck);
        acck = fdot2(f_h2(kv.w), kwr[4*q+3], acck);
      }
      float a = eluf(accq + acck);
      if (act) Ab[rr * 16 + np] = a;
    }

    // ------- alin + softmax (in-place on A rows) -------
    for (int k = 0; k <= 10; ++k) {
      int r = grp + 4 * k;
      bool act = (np < 14) && (r < 42);
      int rr = (r < 42) ? r : 0;
      const f4a* Ar4 = (const f4a*)(Ab + rr * 16);
      float4 P0 = Ar4[0], P1 = Ar4[1], P2 = Ar4[2], P3 = Ar4[3];
      float pr[14] = {P0.x,P0.y,P0.z,P0.w, P1.x,P1.y,P1.z,P1.w,
                      P2.x,P2.y,P2.z,P2.w, P3.x,P3.y};
      float acc = abr;
      #pragma unroll
      for (int i = 0; i < 14; ++i) acc += pr[i] * awr[i];
      float vsc = act ? acc : -__builtin_inff();
      float mx = vsc;
      #pragma unroll
      for (int m2 = 1; m2 < 16; m2 <<= 1) mx = fmaxf(mx, __shfl_xor(mx, m2, 64));
      float e = __expf(vsc - mx);
      float sm = e;
      #pragma unroll
      for (int m2 = 1; m2 < 16; m2 <<= 1) sm += __shfl_xor(sm, m2, 64);
      float p = e * rcpf(sm);
      if (act) Ab[rr * 16 + np] = p;
    }

    // ============ PHASE B: V projection (overlay K) -> LN -> A@V -> head ====
    for (int n = 0; n < 14; ++n) {
      h2 xr0 = xs[n*5+0], xr1 = xs[n*5+1], xr2 = xs[n*5+2], xr3 = xs[n*5+3], xr4 = xs[n*5+4];
      #pragma unroll
      for (int k = 0; k < 2; ++k) {
        float acc = pbB[k];
        acc = fdot2(xr0, pwB[k][0], acc);
        acc = fdot2(xr1, pwB[k][1], acc);
        acc = fdot2(xr2, pwB[k][2], acc);
        acc = fdot2(xr3, pwB[k][3], acc);
        acc = fdot2(xr4, pwB[k][4], acc);
        if (actB[k]) kqvh[cbB[k] + n * 32] = (__fp16)acc;
      }
    }
    doLN(0, vng, vnb, (gf >> 2) & 1u);     // V (overlaid K region)

    // ------- E[n][h*32+d] = sum_m A[r][m] * V[h][m][d]  (f16, overlays Q) ----
    for (int k = 0; k <= 10; ++k) {
      int r = grp + 4 * k;
      bool act = (r < 42);
      int rr = act ? r : 0;
      int h = rr / 14, n = rr - 14 * h;
      const f4a* Ar4 = (const f4a*)(Ab + rr * 16);
      float4 P0 = Ar4[0], P1 = Ar4[1], P2 = Ar4[2], P3 = Ar4[3];
      float pr[14] = {P0.x,P0.y,P0.z,P0.w, P1.x,P1.y,P1.z,P1.w,
                      P2.x,P2.y,P2.z,P2.w, P3.x,P3.y};
      const h2a* Vb = (const h2a*)(kqv + h * 224 + np);
      float accx = 0.f, accy = 0.f;
      #pragma unroll
      for (int m = 0; m < 14; ++m) {
        h2 vv = Vb[m * 16];
        accx += pr[m] * (float)vv.x;
        accy += pr[m] * (float)vv.y;
      }
      if (act) kqv[672 + n * 48 + h * 16 + np] = pkh2(accx, accy);
    }

    // ------- l1: E2[n][j] = relu(E[n]·l1w[j] + b)  (f32, overlays A) -------
    h2 lwr[48];
    #pragma unroll
    for (int i = 0; i < 48; ++i) lwr[i] = s_l1w[j32 * 50 + i];
    for (int k = 0; k < 7; ++k) {
      int n = g2 + 2 * k;
      const f4a* Er = (const f4a*)(kqv + 672 + n * 48);
      float acc0 = l1br, acc1 = 0.f;
      #pragma unroll
      for (int q = 0; q < 12; ++q) {
        float4 ev = Er[q];
        acc0 = fdot2(f_h2(ev.x), lwr[4*q+0], acc0);
        acc1 = fdot2(f_h2(ev.y), lwr[4*q+1], acc1);
        acc0 = fdot2(f_h2(ev.z), lwr[4*q+2], acc0);
        acc1 = fdot2(f_h2(ev.w), lwr[4*q+3], acc1);
      }
      Ab[n * 32 + j32] = fmaxf(acc0 + acc1, 0.f);
    }

    // ------- LN2 (448, no affine) + max over n + l2 -> y -------
    float sum2 = 0.f, sq2 = 0.f;
    #pragma unroll
    for (int m = 0; m < 7; ++m) {
      float v = Ab[lane + 64 * m];
      sum2 += v; sq2 += v * v;
    }
    #pragma unroll
    for (int m2 = 1; m2 < 64; m2 <<= 1) { sum2 += __shfl_xor(sum2, m2, 64); sq2 += __shfl_xor(sq2, m2, 64); }
    float mean2 = sum2 * (1.f / 448.f);
    float var2  = sq2  * (1.f / 448.f) - mean2 * mean2;
    float sc2   = rsqrtf(var2 + 1e-5f);
    float mx = -__builtin_inff();
    #pragma unroll
    for (int k = 0; k < 7; ++k) mx = fmaxf(mx, Ab[(g2 + 2 * k) * 32 + j32]);
    mx = fmaxf(mx, __shfl_xor(mx, 32, 64));
    float Md = (mx - mean2) * sc2;               // scale>0: max commutes with LN
    float vd = (lane < 32) ? Md * l2r : 0.f;
    #pragma unroll
    for (int m2 = 1; m2 < 64; m2 <<= 1) vd += __shfl_xor(vd, m2, 64);
    float yy = eluf(vd + l2bb);
    if (lane == 0) out[s] = yy;
  }
}

// ---------------------------------------------------------------------------
// Kernel 2: out[s] = sigmoid(fc3 · tanh(fc2 · tanh(fc1*y + b1) + b2) + b3)
// Applied in place on d_out (kernel 1 left y there).
// ---------------------------------------------------------------------------
__global__ __launch_bounds__(256) void mlp_head(
    float* __restrict__ out,
    const float* __restrict__ fc1w, const float* __restrict__ fc1b,
    const float* __restrict__ fc2w, const float* __restrict__ fc2b,
    const float* __restrict__ fc3w, const float* __restrict__ fc3b, int B)
{
  __shared__ float s1w[100], s1b[100];
  __shared__ __align__(16) h2 s2w[100 * 52];   // rows padded to 52 pairs (zeros)
  __shared__ float s2b[100], s3w[100];
  __shared__ float s3b[1];
  const int tid = threadIdx.x;
  for (int i = tid; i < 100; i += 256) {
    s1w[i] = fc1w[i]; s1b[i] = fc1b[i]; s2b[i] = fc2b[i]; s3w[i] = fc3w[i];
  }
  for (int i = tid; i < 5200; i += 256) {
    int r = i / 52, c2 = i - 52 * r;
    s2w[i] = (c2 < 50) ? pkh2(fc2w[r * 100 + 2 * c2], fc2w[r * 100 + 2 * c2 + 1])
                       : pkh2(0.f, 0.f);
  }
  if (tid == 0) s3b[0] = fc3b[0];
  __syncthreads();

  const int sid = blockIdx.x * 256 + tid;
  if (sid >= B) return;
  const float y = out[sid];

  h2 a6[52];
  #pragma unroll
  for (int j2 = 0; j2 < 50; ++j2) {
    float t0 = tanhf_fast(y * s1w[2 * j2]     + s1b[2 * j2]);
    float t1 = tanhf_fast(y * s1w[2 * j2 + 1] + s1b[2 * j2 + 1]);
    a6[j2] = pkh2(t0, t1);
  }
  a6[50] = pkh2(0.f, 0.f);
  a6[51] = pkh2(0.f, 0.f);

  float logit = s3b[0];
  for (int i = 0; i < 100; ++i) {
    const f4a* row = (const f4a*)(s2w + i * 52);
    float acc0 = s2b[i], acc1 = 0.f;
    #pragma unroll
    for (int q = 0; q < 13; ++q) {
      float4 rv = row[q];
      acc0 = fdot2(f_h2(rv.x), a6[4*q+0], acc0);
      acc1 = fdot2(f_h2(rv.y), a6[4*q+1], acc1);
      acc0 = fdot2(f_h2(rv.z), a6[4*q+2], acc0);
      acc1 = fdot2(f_h2(rv.w), a6[4*q+3], acc1);
    }
    logit += tanhf_fast(acc0 + acc1) * s3w[i];
  }
  out[sid] = rcpf(1.f + __expf(-logit));
}

// ---------------------------------------------------------------------------
extern "C" void kernel_launch(void* const* d_in, const int* in_sizes, int n_in,
                              void* d_out, int out_size, void* d_ws, size_t ws_size,
                              hipStream_t stream) {
  (void)d_ws; (void)ws_size; (void)n_in; (void)out_size;
  const float* x     = (const float*)d_in[0];
  const float* kw    = (const float*)d_in[1];
  const float* kb    = (const float*)d_in[2];
  const float* qw    = (const float*)d_in[3];
  const float* qb    = (const float*)d_in[4];
  const float* vw    = (const float*)d_in[5];
  const float* vb    = (const float*)d_in[6];
  const float* kng   = (const float*)d_in[7];
  const float* knb   = (const float*)d_in[8];
  const float* qng   = (const float*)d_in[9];
  const float* qnb   = (const float*)d_in[10];
  const float* vng   = (const float*)d_in[11];
  const float* vnb   = (const float*)d_in[12];
  const float* klinw = (const float*)d_in[13];
  const float* klinb = (const float*)d_in[14];
  const float* qlinw = (const float*)d_in[15];
  const float* qlinb = (const float*)d_in[16];
  const float* alinw = (const float*)d_in[17];
  const float* alinb = (const float*)d_in[18];
  const float* l1w   = (const float*)d_in[19];
  const float* l1b   = (const float*)d_in[20];
  const float* l2w   = (const float*)d_in[21];
  const float* l2b   = (const float*)d_in[22];
  const float* fc1w  = (const float*)d_in[23];
  const float* fc1b  = (const float*)d_in[24];
  const float* fc2w  = (const float*)d_in[25];
  const float* fc2b  = (const float*)d_in[26];
  const float* fc3w  = (const float*)d_in[27];
  const float* fc3b  = (const float*)d_in[28];
  float* out = (float*)d_out;
  const int B = in_sizes[0] / 140;

  fused_main<<<768, 256, 0, stream>>>(x, kw, kb, qw, qb, vw, vb,
      kng, knb, qng, qnb, vng, vnb, klinw, klinb, qlinw, qlinb,
      alinw, alinb, l1w, l1b, l2w, l2b, out, B);
  mlp_head<<<(B + 255) / 256, 256, 0, stream>>>(out, fc1w, fc1b, fc2w, fc2b,
      fc3w, fc3b, B);
}